// Round 1
// baseline (93.552 us; speedup 1.0000x reference)
//
#include <hip/hip_runtime.h>
#include <stdint.h>

#define NF    64
#define QN    16
#define DIM0  50000
#define SROWS 100000

// ---------------------------------------------------------------------------
// Pass 1: quantize feats -> 4-bit codes, packed 8 feats per u32 (8 u32 / row).
// Literal argmin over the 16 candidates (strict < keeps first index, matching
// jnp.argmin tie-break). Candidates staged in LDS (2*64*16 floats = 8 KB).
// ---------------------------------------------------------------------------
__global__ void quantize_kernel(const float* __restrict__ feats,
                                const float* __restrict__ cand,
                                uint32_t* __restrict__ qcodes, int nwords) {
    __shared__ float scand[2 * NF * QN];
    for (int i = threadIdx.x; i < 2 * NF * QN; i += blockDim.x)
        scand[i] = cand[i];
    __syncthreads();

    int gid = blockIdx.x * blockDim.x + threadIdx.x;   // word index: s*8 + w
    if (gid >= nwords) return;
    int s = gid >> 3;
    int w = gid & 7;
    int axis = (s >= DIM0) ? 1 : 0;

    const float* frow  = feats + (size_t)s * NF + w * 8;
    const float* cbase = scand + axis * NF * QN;

    uint32_t word = 0u;
#pragma unroll
    for (int j = 0; j < 8; ++j) {
        float fv = frow[j];
        const float* c = cbase + (w * 8 + j) * QN;
        float best = fabsf(fv - c[0]);
        uint32_t q = 0u;
#pragma unroll
        for (int k = 1; k < QN; ++k) {
            float d = fabsf(fv - c[k]);
            if (d < best) { best = d; q = (uint32_t)k; }
        }
        word |= q << (4 * j);
    }
    qcodes[gid] = word;
}

// ---------------------------------------------------------------------------
// Pass 2: per-query bilinear contraction.
//   a = decode(codeA[f]), b = decode(codeB[f])   (decode is bit-exact qkeys)
//   t[f] = V0*a*b + V1*a*(1-b) + V2*(1-a)*b + V3*(1-a)*(1-b)
//   out = sum(t[0:32]) * tanh(sum(t[32:64])) * exp(scale) + bias
// ---------------------------------------------------------------------------
__global__ void query_kernel(const uint32_t* __restrict__ qcodes,
                             const float* __restrict__ values,
                             const float* __restrict__ scale,
                             const float* __restrict__ bias,
                             const int* __restrict__ idx0,
                             const int* __restrict__ idx1,
                             float* __restrict__ out, int N) {
    __shared__ float V[4 * NF];
    if (threadIdx.x < 4 * NF) V[threadIdx.x] = values[threadIdx.x];
    __syncthreads();

    int n = blockIdx.x * blockDim.x + threadIdx.x;
    if (n >= N) return;

    int r0 = idx0[n];
    int r1 = DIM0 + idx1[n];

    const uint4* pa = (const uint4*)(qcodes + (size_t)r0 * 8);
    const uint4* pb = (const uint4*)(qcodes + (size_t)r1 * 8);
    uint4 a0 = pa[0], a1 = pa[1];
    uint4 b0 = pb[0], b1 = pb[1];
    uint32_t aw[8] = {a0.x, a0.y, a0.z, a0.w, a1.x, a1.y, a1.z, a1.w};
    uint32_t bw[8] = {b0.x, b0.y, b0.z, b0.w, b1.x, b1.y, b1.z, b1.w};

    float asum = 0.0f, bsum = 0.0f;
#pragma unroll
    for (int wd = 0; wd < 8; ++wd) {
        uint32_t wa = aw[wd];
        uint32_t wb = bw[wd];
#pragma unroll
        for (int j = 0; j < 8; ++j) {
            int f = wd * 8 + j;
            float a = 0.03125f + 0.0625f * (float)((wa >> (4 * j)) & 15u);
            float b = 0.03125f + 0.0625f * (float)((wb >> (4 * j)) & 15u);
            float ia = 1.0f - a;
            float ib = 1.0f - b;
            float t = V[f]          * (a * b)
                    + V[NF + f]     * (a * ib)
                    + V[2 * NF + f] * (ia * b)
                    + V[3 * NF + f] * (ia * ib);
            if (f < 32) asum += t; else bsum += t;
        }
    }
    out[n] = asum * tanhf(bsum) * expf(scale[0]) + bias[0];
}

extern "C" void kernel_launch(void* const* d_in, const int* in_sizes, int n_in,
                              void* d_out, int out_size, void* d_ws, size_t ws_size,
                              hipStream_t stream) {
    const float* values = (const float*)d_in[0];  // [1,4,64]
    const float* feats  = (const float*)d_in[1];  // [100000,64]
    const float* cand   = (const float*)d_in[2];  // [2,64,16]
    const float* scale  = (const float*)d_in[3];  // [1]
    const float* bias   = (const float*)d_in[4];  // [1]
    const int*   idx0   = (const int*)d_in[5];    // [N]
    const int*   idx1   = (const int*)d_in[6];    // [N]
    float*       out    = (float*)d_out;          // [N] f32

    uint32_t* qcodes = (uint32_t*)d_ws;           // SROWS*8 u32 = 3.2 MB

    int nwords = SROWS * 8;
    int tpb = 256;
    quantize_kernel<<<(nwords + tpb - 1) / tpb, tpb, 0, stream>>>(
        feats, cand, qcodes, nwords);

    int N = out_size;
    query_kernel<<<(N + tpb - 1) / tpb, tpb, 0, stream>>>(
        qcodes, values, scale, bias, idx0, idx1, out, N);
}

// Round 2
// 39.273 us; speedup vs baseline: 2.3821x; 2.3821x over previous
//
#include <hip/hip_runtime.h>
#include <stdint.h>

#define NF    64
#define DIM0  50000
#define SROWS 100000

// ws layout (bytes):
//   [0, 3.2M)      : qcodes, 8 u32 per row (4-bit codes, 8 feats/word)
//   [3.2M, 4.0M)   : per-row float2 partial sums (axis-dependent, C folded into axis0)
#define SUMS_OFF_BYTES (SROWS * 32)

// ---------------------------------------------------------------------------
// Pass 1: closed-form quantize + per-row partial sums.
//   q = clamp(ceil(16*f - 1), 0, 15)   (bit-exact vs argmin incl. tie->lower)
//   axis0 row s: sums[s] = { Sum_{f<32}(X'_f A_f + C_f), Sum_{f>=32}(X'_f A_f + C_f) }
//   axis1 row s: sums[s] = { Sum_{f<32}(Y'_f B_f),       Sum_{f>=32}(Y'_f B_f) }
// where W=V0-V1-V2+V3, X'=W/512+(V1-V3)/16, Y'=W/512+(V2-V3)/16,
//       C = W/1024 + (V1+V2-2*V3)/32 + V3
// 8 threads per row (8 feats each) -> coalesced loads, shuffle-reduce sums.
// ---------------------------------------------------------------------------
__global__ void quantize_kernel(const float* __restrict__ feats,
                                const float* __restrict__ values,
                                uint32_t* __restrict__ qcodes,
                                float2* __restrict__ sums) {
    __shared__ float sT0[NF];  // X' (axis0 linear coeff)
    __shared__ float sT1[NF];  // Y' (axis1 linear coeff)
    __shared__ float sC[NF];   // constant term (folded into axis0)
    int t = threadIdx.x;
    if (t < NF) {
        float v0 = values[t], v1 = values[NF + t];
        float v2 = values[2 * NF + t], v3 = values[3 * NF + t];
        float W = v0 - v1 - v2 + v3;
        float X = v1 - v3, Y = v2 - v3;
        sT0[t] = W * (1.0f / 512.0f) + X * (1.0f / 16.0f);
        sT1[t] = W * (1.0f / 512.0f) + Y * (1.0f / 16.0f);
        sC[t]  = W * (1.0f / 1024.0f) + (X + Y) * (1.0f / 32.0f) + v3;
    }
    __syncthreads();

    int gid = blockIdx.x * blockDim.x + t;   // word index: s*8 + w  (exact grid)
    int s = gid >> 3;
    int w = gid & 7;
    bool axis0 = (s < DIM0);

    const float4* fr = (const float4*)(feats + (size_t)s * NF + w * 8);
    float4 fA = fr[0], fB = fr[1];
    float fv[8] = {fA.x, fA.y, fA.z, fA.w, fB.x, fB.y, fB.z, fB.w};

    uint32_t word = 0u;
    float partial = 0.0f;
#pragma unroll
    for (int j = 0; j < 8; ++j) {
        int f = w * 8 + j;
        float x = fmaf(fv[j], 16.0f, -1.0f);   // exact: 16f-1 representable
        int q = (int)ceilf(x);
        q = q < 0 ? 0 : (q > 15 ? 15 : q);
        word |= (uint32_t)q << (4 * j);
        float T = axis0 ? sT0[f] : sT1[f];
        partial = fmaf(T, (float)q, partial);
        if (axis0) partial += sC[f];
    }
    qcodes[gid] = word;

    // reduce the 4 threads of each half (w 0..3 -> f<32, w 4..7 -> f>=32)
    partial += __shfl_xor(partial, 1);
    partial += __shfl_xor(partial, 2);
    float other = __shfl_xor(partial, 4);
    if (w == 0) sums[s] = make_float2(partial, other);
}

// ---------------------------------------------------------------------------
// Pass 2: per-query cross term + precomputed row sums.
//   asum = Sum_{f<32} W'_f A_f B_f + sums0(r0).x + sums1(r1).x
//   bsum = Sum_{f>=32} ...        + sums0(r0).y + sums1(r1).y
//   out  = asum * tanh(bsum) * exp(scale) + bias
// Inner loop per feature: 2x bfe, 1x mul_u24, 1x cvt, 1x fma.
// ---------------------------------------------------------------------------
__global__ void query_kernel(const uint32_t* __restrict__ qcodes,
                             const float2* __restrict__ sums,
                             const float* __restrict__ values,
                             const float* __restrict__ scale,
                             const float* __restrict__ bias,
                             const int* __restrict__ idx0,
                             const int* __restrict__ idx1,
                             float* __restrict__ out, int N) {
    __shared__ float sW[NF];   // W' = (V0-V1-V2+V3)/256
    if (threadIdx.x < NF) {
        int t = threadIdx.x;
        float v0 = values[t], v1 = values[NF + t];
        float v2 = values[2 * NF + t], v3 = values[3 * NF + t];
        sW[t] = (v0 - v1 - v2 + v3) * (1.0f / 256.0f);
    }
    __syncthreads();

    int n = blockIdx.x * blockDim.x + threadIdx.x;
    if (n >= N) return;

    int r0 = idx0[n];
    int r1 = DIM0 + idx1[n];

    const uint4* pa = (const uint4*)(qcodes + (size_t)r0 * 8);
    const uint4* pb = (const uint4*)(qcodes + (size_t)r1 * 8);
    uint4 a0 = pa[0], a1 = pa[1];
    uint4 b0 = pb[0], b1 = pb[1];
    float2 sa = sums[r0];
    float2 sb = sums[r1];

    uint32_t aw[8] = {a0.x, a0.y, a0.z, a0.w, a1.x, a1.y, a1.z, a1.w};
    uint32_t bw[8] = {b0.x, b0.y, b0.z, b0.w, b1.x, b1.y, b1.z, b1.w};

    float ca = 0.0f, cb = 0.0f;
#pragma unroll
    for (int wd = 0; wd < 8; ++wd) {
        uint32_t wa = aw[wd];
        uint32_t wb = bw[wd];
#pragma unroll
        for (int j = 0; j < 8; ++j) {
            int f = wd * 8 + j;
            uint32_t A = (wa >> (4 * j)) & 15u;
            uint32_t B = (wb >> (4 * j)) & 15u;
            float p = (float)(A * B);                 // exact, <= 225
            if (f < 32) ca = fmaf(p, sW[f], ca);
            else        cb = fmaf(p, sW[f], cb);
        }
    }

    float asum = ca + sa.x + sb.x;
    float bsum = cb + sa.y + sb.y;
    out[n] = asum * tanhf(bsum) * expf(scale[0]) + bias[0];
}

extern "C" void kernel_launch(void* const* d_in, const int* in_sizes, int n_in,
                              void* d_out, int out_size, void* d_ws, size_t ws_size,
                              hipStream_t stream) {
    const float* values = (const float*)d_in[0];  // [1,4,64]
    const float* feats  = (const float*)d_in[1];  // [100000,64]
    const float* scale  = (const float*)d_in[3];  // [1]
    const float* bias   = (const float*)d_in[4];  // [1]
    const int*   idx0   = (const int*)d_in[5];    // [N]
    const int*   idx1   = (const int*)d_in[6];    // [N]
    float*       out    = (float*)d_out;          // [N] f32

    uint32_t* qcodes = (uint32_t*)d_ws;
    float2*   sums   = (float2*)((char*)d_ws + SUMS_OFF_BYTES);

    int tpb = 256;
    int nwords = SROWS * 8;                        // 800000 = 3125 * 256 exact
    quantize_kernel<<<nwords / tpb, tpb, 0, stream>>>(feats, values, qcodes, sums);

    int N = out_size;
    query_kernel<<<(N + tpb - 1) / tpb, tpb, 0, stream>>>(
        qcodes, sums, values, scale, bias, idx0, idx1, out, N);
}